// Round 8
// baseline (137.057 us; speedup 1.0000x reference)
//
#include <hip/hip_runtime.h>
#include <hip/hip_bf16.h>

// Segment-mean gather (AGGR_MEAN graph pooling).
//   input [N=100000, C=128] f32; idxn [E] int; seg_ids [E] int (sorted);
//   degs [N_OUT=50000] int; out [N_OUT, C] f32.
//
// R8: R7 (4 edges per dwordx4) got 57.6us, VALUBusy 49%, occ 42% — the wave
// alternates {8-load burst -> vmcnt drain -> ~130 VALU consume}, serializing
// latency and VALU, and deg>32 loops twice. deg<=63 => ONE 64-edge chunk:
// issue all 16 dwordx4 gathers up front (16KB in flight/wave), consume with
// wave-uniform per-group guards (4k < cl) so nonexistent edges cost no VALU.
// Binary search inlined (starts kernel dropped, 2 launches total).

typedef float fvec4 __attribute__((ext_vector_type(4)));

static __device__ inline uint16_t f2bf_rne(float f) {
  uint32_t u = __float_as_uint(f);
  return (uint16_t)((u + 0x7fffu + ((u >> 16) & 1u)) >> 16);
}

// ---- pass 1: f32 [N][128] -> packed bf16 [N][64 u32] (flat) ---------------
__global__ __launch_bounds__(256) void cvt_bf16_kernel(
    const float* __restrict__ in, uint32_t* __restrict__ tab, int npairs2) {
  const float4* __restrict__ in4 = (const float4*)in;
  uint2* __restrict__ o2 = (uint2*)tab;
  int i = blockIdx.x * blockDim.x + threadIdx.x;
  const int stride = gridDim.x * blockDim.x;
  for (; i < npairs2; i += stride) {
    float4 v = in4[i];
    uint2 r;
    r.x = (uint32_t)f2bf_rne(v.x) | ((uint32_t)f2bf_rne(v.y) << 16);
    r.y = (uint32_t)f2bf_rne(v.z) | ((uint32_t)f2bf_rne(v.w) << 16);
    o2[i] = r;
  }
}

// ---- pass 2: gather+mean ---------------------------------------------------
// wave = 1 segment. lane: slot = t>>4 (edge within group of 4), cw = t&15
// (16B chunk of the 256B row = channels cw*8..cw*8+8). All 16 dwordx4
// gathers (64 edges, clamped) issued before any consume.
__global__ __launch_bounds__(256) void seg_mean_x4_kernel(
    const uint4* __restrict__ tab,   // [n_nodes][16] uint4 rows
    const int* __restrict__ idxn,
    const int* __restrict__ seg_ids,
    const int* __restrict__ degs,
    float* __restrict__ out,
    int n_out, int E) {
  const int wave = threadIdx.x >> 6;
  const int s = blockIdx.x * 4 + wave;
  if (s >= n_out) return;
  const int t = threadIdx.x & 63;
  const int slot = t >> 4;
  const int cw = t & 15;

  const int deg = degs[s];

  // lower_bound(seg_ids, s) — wave-uniform broadcast loads.
  int lo = 0, hi = E;
  while (lo < hi) {
    int mid = (lo + hi) >> 1;
    if (seg_ids[mid] < s) lo = mid + 1; else hi = mid;
  }
  const int start = lo;

  float acc[8];
#pragma unroll
  for (int j = 0; j < 8; ++j) acc[j] = 0.f;

  for (int cb = 0; cb < deg; cb += 64) {  // deg<=63 -> exactly one pass
    const int cl = min(deg - cb, 64);
    const int clm1 = cl - 1;
    // one coalesced load covers this chunk's edge indices
    const int idx_t = idxn[start + cb + (t < cl ? t : clm1)];

    // burst: all 16 gathers in flight (clamped -> always legal)
    uint4 v[16];
#pragma unroll
    for (int k = 0; k < 16; ++k) {
      const int e = 4 * k + slot;
      const int node = __shfl(idx_t, e < clm1 ? e : clm1, 64);
      v[k] = tab[(size_t)node * 16 + cw];
    }

    // consume: group k live iff 4k < cl (wave-uniform guard)
#pragma unroll
    for (int k = 0; k < 16; ++k) {
      if (4 * k < cl) {
        const uint32_t* p = (const uint32_t*)&v[k];
        if (4 * k + 4 <= cl) {  // full group, no masks
#pragma unroll
          for (int j = 0; j < 4; ++j) {
            acc[2 * j]     += __uint_as_float(p[j] << 16);
            acc[2 * j + 1] += __uint_as_float(p[j] & 0xffff0000u);
          }
        } else {  // boundary group
          const float w = (4 * k + slot < cl) ? 1.0f : 0.0f;
#pragma unroll
          for (int j = 0; j < 4; ++j) {
            acc[2 * j]     = fmaf(__uint_as_float(p[j] << 16), w, acc[2 * j]);
            acc[2 * j + 1] = fmaf(__uint_as_float(p[j] & 0xffff0000u), w,
                                  acc[2 * j + 1]);
          }
        }
      }
    }
  }

  // reduce across the 4 edge slots (lane bits 4,5)
#pragma unroll
  for (int j = 0; j < 8; ++j) {
    acc[j] += __shfl_xor(acc[j], 16, 64);
    acc[j] += __shfl_xor(acc[j], 32, 64);
  }

  if (t < 16) {
    const float inv = (deg > 0) ? (1.0f / (float)deg) : 0.0f;
    fvec4 r0, r1;
    r0.x = acc[0] * inv; r0.y = acc[1] * inv;
    r0.z = acc[2] * inv; r0.w = acc[3] * inv;
    r1.x = acc[4] * inv; r1.y = acc[5] * inv;
    r1.z = acc[6] * inv; r1.w = acc[7] * inv;
    fvec4* dst = (fvec4*)(out + (size_t)s * 128 + t * 8);
    dst[0] = r0;
    dst[1] = r1;
  }
}

// ---- fallback (ws too small for the bf16 table): direct f32 gather --------
__global__ __launch_bounds__(64) void seg_mean_f32_kernel(
    const float* __restrict__ input,
    const int* __restrict__ idxn,
    const int* __restrict__ seg_ids,
    const int* __restrict__ degs,
    float* __restrict__ out,
    int n_out, int E) {
  const int s = blockIdx.x;
  if (s >= n_out) return;
  const int deg = degs[s];
  const int t = threadIdx.x;
  int lo = 0, hi = E;
  while (lo < hi) {
    int mid = (lo + hi) >> 1;
    if (seg_ids[mid] < s) lo = mid + 1; else hi = mid;
  }
  const int start = lo;
  const float2* __restrict__ in2 = (const float2*)input;
  float accx = 0.f, accy = 0.f;
  int e = 0;
  for (; e + 8 <= deg; e += 8) {
    int n[8];
#pragma unroll
    for (int k = 0; k < 8; ++k) n[k] = idxn[start + e + k];
    float2 v[8];
#pragma unroll
    for (int k = 0; k < 8; ++k) v[k] = in2[(size_t)n[k] * 64 + t];
#pragma unroll
    for (int k = 0; k < 8; ++k) { accx += v[k].x; accy += v[k].y; }
  }
  for (; e < deg; ++e) {
    const int node = idxn[start + e];
    const float2 v = in2[(size_t)node * 64 + t];
    accx += v.x;
    accy += v.y;
  }
  const float inv = (deg > 0) ? (1.0f / (float)deg) : 0.0f;
  float2 r;
  r.x = accx * inv;
  r.y = accy * inv;
  ((float2*)out)[(size_t)s * 64 + t] = r;
}

extern "C" void kernel_launch(void* const* d_in, const int* in_sizes, int n_in,
                              void* d_out, int out_size, void* d_ws, size_t ws_size,
                              hipStream_t stream) {
  const float* input  = (const float*)d_in[0];
  const int* idxn     = (const int*)d_in[1];
  const int* seg_ids  = (const int*)d_in[2];
  const int* degs     = (const int*)d_in[3];
  float* out          = (float*)d_out;

  const int n_elem = in_sizes[0];   // N * C
  const int E      = in_sizes[1];
  const int n_out  = in_sizes[3];

  const size_t tab_bytes = (size_t)n_elem * 2;

  if (ws_size >= tab_bytes) {
    uint32_t* tab = (uint32_t*)d_ws;
    cvt_bf16_kernel<<<2048, 256, 0, stream>>>(input, tab, n_elem / 4);
    seg_mean_x4_kernel<<<(n_out + 3) / 4, 256, 0, stream>>>(
        (const uint4*)tab, idxn, seg_ids, degs, out, n_out, E);
  } else {
    seg_mean_f32_kernel<<<n_out, 64, 0, stream>>>(input, idxn, seg_ids, degs,
                                                  out, n_out, E);
  }
}